// Round 1
// baseline (477.917 us; speedup 1.0000x reference)
//
#include <hip/hip_runtime.h>
#include <math.h>

// ---------------- config ----------------
// JAX dropout RNG scheme: 1 = jax_threefry_partitionable (modern default),
// 0 = original/legacy threefry counter layout. Flip if absmax ~1e-3..5e-3.
#define JAX_PARTITIONABLE 1

#define Bsz 4
#define Nn  4096
#define Dd  64
#define TOT (Bsz*Nn*Dd)          // 1048576
#define HALF (TOT/2)             // 524288

typedef unsigned int u32;
typedef unsigned long long u64;
typedef short short8 __attribute__((ext_vector_type(8)));
typedef float f32x4 __attribute__((ext_vector_type(4)));

// ---------------- helpers ----------------
__device__ __forceinline__ unsigned short bf16_of(float x) {
  u32 u = __float_as_uint(x);
  u32 r = (u + 0x7FFFu + ((u >> 16) & 1u)) >> 16;   // RNE
  return (unsigned short)r;
}
__device__ __forceinline__ u32 pack2(float a, float b) {
  return (u32)bf16_of(a) | ((u32)bf16_of(b) << 16);
}
__device__ __forceinline__ void gll16(const void* g, void* l) {
  // async global->LDS, 16B/lane, dest = wave-uniform base + lane*16
  __builtin_amdgcn_global_load_lds((const __attribute__((address_space(1))) void*)g,
                                   (__attribute__((address_space(3))) void*)l, 16, 0, 0);
}

// Threefry-2x32 (exact JAX rotation/key schedule)
__device__ __forceinline__ void tf(u32 k0, u32 k1, u32 x0, u32 x1, u32& y0, u32& y1) {
  u32 ks2 = k0 ^ k1 ^ 0x1BD11BDAu;
  x0 += k0; x1 += k1;
#define TFR(r) { x0 += x1; x1 = (x1 << (r)) | (x1 >> (32 - (r))); x1 ^= x0; }
  TFR(13) TFR(15) TFR(26) TFR(6)
  x0 += k1; x1 += ks2 + 1u;
  TFR(17) TFR(29) TFR(16) TFR(24)
  x0 += ks2; x1 += k0 + 2u;
  TFR(13) TFR(15) TFR(26) TFR(6)
  x0 += k0; x1 += k1 + 3u;
  TFR(17) TFR(29) TFR(16) TFR(24)
  x0 += k1; x1 += ks2 + 4u;
  TFR(13) TFR(15) TFR(26) TFR(6)
  x0 += ks2; x1 += k0 + 5u;
#undef TFR
  y0 = x0; y1 = x1;
}

// bit->bf16 expansion: byte (8 bits, pre-permuted by sigma in k_bits) -> 8 bf16 {0,1}
// mul-spread: nib*0x204081 & 0x01010101 puts bits in byte lanes; (..&0x10001)*0x3F80
// packs two {0,1} into two bf16 halves. Element order: e=(b0,b2,b1,b3,b4,b6,b5,b7),
// compensated by the sigma permutation at bitmask build time.
__device__ __forceinline__ short8 expand_byte(u32 byte) {
  u32 lo = byte & 15u, hi = (byte >> 4) & 15u;
  u32 s0 = (lo * 0x00204081u) & 0x01010101u;
  u32 s1 = (hi * 0x00204081u) & 0x01010101u;
  union { u32 u[4]; short8 v; } r;
  r.u[0] = (s0 & 0x00010001u) * 0x3F80u;
  r.u[1] = ((s0 >> 8) & 0x00010001u) * 0x3F80u;
  r.u[2] = (s1 & 0x00010001u) * 0x3F80u;
  r.u[3] = ((s1 >> 8) & 0x00010001u) * 0x3F80u;
  return r.v;
}

// ---------------- kernel 1: adj -> bitmask + dinv ----------------
// one block per (b,i) row; 4 waves x 16 iters x 64 lanes = 4096 int32 reads.
// lane l loads column sigma(l)=... (permuted within bytes to match expand_byte order)
__global__ __launch_bounds__(256) void k_bits(const int* __restrict__ adj,
                                              u64* __restrict__ bits,
                                              float* __restrict__ dinv) {
  int row = blockIdx.x;              // b*N + i
  int i = row & (Nn - 1);
  int lane = threadIdx.x & 63;
  int wv = threadIdx.x >> 6;
  __shared__ int cnts[4];
  int l7 = lane & 7;
  int m = ((l7 ^ (l7 >> 1)) & 1);    // tau: swap 1<->2, 5<->6
  int sig = (lane & 56) | (l7 ^ (m * 3));
  const int* rowp = adj + (size_t)row * Nn;
  int base = wv * 1024;
  int myc = 0;
#pragma unroll
  for (int k = 0; k < 16; ++k) {
    int j = base + k * 64 + sig;
    int v = rowp[j];
    bool pred = (v != 0) || (j == i);   // self-loop forced
    u64 bm = __ballot(pred);
    if (lane == 0) {
      bits[(size_t)row * 64 + wv * 16 + k] = bm;
      myc += __popcll(bm);
    }
  }
  if (lane == 0) cnts[wv] = myc;
  __syncthreads();
  if (threadIdx.x == 0) {
    int deg = cnts[0] + cnts[1] + cnts[2] + cnts[3];
    dinv[row] = (float)(1.0 / sqrt((double)deg));
  }
}

// ---------------- kernel 2: dropout masks (exact JAX threefry) ----------------
__global__ __launch_bounds__(256) void k_masks(unsigned char* __restrict__ masks) {
#if JAX_PARTITIONABLE
  // split(key(42)) fold-like: key_i = threefry((0,42), (0, i)) full pair
  u32 k1a, k1b, k2a, k2b;
  tf(0u, 42u, 0u, 0u, k1a, k1b);
  tf(0u, 42u, 0u, 1u, k2a, k2b);
  int tid = blockIdx.x * 256 + threadIdx.x;     // [0, 2*TOT)
  int layer = tid >> 20;
  u32 f = (u32)(tid & (TOT - 1));
  u32 ka = layer ? k2a : k1a, kb = layer ? k2b : k1b;
  u32 h0, h1; tf(ka, kb, 0u, f, h0, h1);
  u32 bitsv = h0 ^ h1;                          // 32-bit fold
  float u = __uint_as_float((bitsv >> 9) | 0x3F800000u) - 1.0f;
  masks[tid] = (u < 0.8f) ? 1 : 0;
#else
  // legacy: split via iota(4) halves; bits via iota(TOT) halves
  u32 a0, b0, a1, b1;
  tf(0u, 42u, 0u, 2u, a0, b0);
  tf(0u, 42u, 1u, 3u, a1, b1);
  u32 k1a = a0, k1b = a1, k2a = b0, k2b = b1;
  int tid = blockIdx.x * 256 + threadIdx.x;     // [0, 2*HALF)
  int layer = tid >> 19;
  u32 p = (u32)(tid & (HALF - 1));
  u32 ka = layer ? k2a : k1a, kb = layer ? k2b : k1b;
  u32 y0, y1; tf(ka, kb, p, (u32)HALF + p, y0, y1);
  unsigned char* mb = masks + (size_t)layer * TOT;
  float u0 = __uint_as_float((y0 >> 9) | 0x3F800000u) - 1.0f;
  float u1 = __uint_as_float((y1 >> 9) | 0x3F800000u) - 1.0f;
  mb[p] = (u0 < 0.8f) ? 1 : 0;
  mb[p + HALF] = (u1 < 0.8f) ? 1 : 0;
#endif
}

// ---------------- kernel 3: Yt = swizzled-transpose( dinv .* (X @ W) ) bf16 ----
// 64-row tile per block; MFMA 16x16x32 bf16.
__global__ __launch_bounds__(256) void k_xw(const float* __restrict__ X,
                                            const float* __restrict__ W,
                                            const float* __restrict__ dinv,
                                            unsigned short* __restrict__ Yt) {
  __shared__ __align__(16) unsigned short Xl[64][72];  // +8 pad: stride 144B (=16 mod 128)
  __shared__ __align__(16) unsigned short Wt[64][72];  // W transposed [d][k]
  __shared__ float dl[64];
  int tid = threadIdx.x;
  int gi0 = blockIdx.x * 64;            // global row b*N + i
#pragma unroll
  for (int it = 0; it < 8; ++it) {      // X tile: 2048 bf16-pairs
    int p = it * 256 + tid;
    int r = p >> 5, c2 = (p & 31) * 2;
    const float* src = X + (size_t)(gi0 + r) * Dd + c2;
    *(u32*)&Xl[r][c2] = pack2(src[0], src[1]);
  }
#pragma unroll
  for (int it = 0; it < 16; ++it) {     // W: 4096 elems, transposed into Wt[d][k]
    int e = it * 256 + tid;
    int k = e >> 6, d = e & 63;
    Wt[d][k] = bf16_of(W[e]);
  }
  if (tid < 64) dl[tid] = dinv[gi0 + tid];
  __syncthreads();

  int lane = tid & 63, wv = tid >> 6;
  int q = lane >> 4, ln = lane & 15;
  f32x4 acc[4];
#pragma unroll
  for (int t = 0; t < 4; ++t) { acc[t][0]=0.f; acc[t][1]=0.f; acc[t][2]=0.f; acc[t][3]=0.f; }
#pragma unroll
  for (int ks = 0; ks < 2; ++ks) {
    short8 a = *(short8*)&Xl[wv * 16 + ln][ks * 32 + q * 8];
#pragma unroll
    for (int t = 0; t < 4; ++t) {
      short8 bfr = *(short8*)&Wt[t * 16 + ln][ks * 32 + q * 8];
      acc[t] = __builtin_amdgcn_mfma_f32_16x16x32_bf16(a, bfr, acc[t], 0, 0, 0);
    }
  }
  int b = gi0 >> 12;
  int i_in_b = gi0 & (Nn - 1);
#pragma unroll
  for (int t = 0; t < 4; ++t) {
    int d = t * 16 + ln;
    int j0 = i_in_b + wv * 16 + q * 4;  // node index of first of 4 rows
    unsigned short h[4];
#pragma unroll
    for (int r = 0; r < 4; ++r) h[r] = bf16_of(acc[t][r] * dl[wv * 16 + q * 4 + r]);
    int byte0 = (2 * j0) & 511;
    int blk = (2 * j0) >> 9;
    size_t off = ((size_t)b * 64 + d) * (Nn * 2) + ((size_t)blk << 9)
               + (size_t)(byte0 ^ ((d & 7) << 4));     // XOR swizzle per d
    uint2 st; st.x = (u32)h[0] | ((u32)h[1] << 16); st.y = (u32)h[2] | ((u32)h[3] << 16);
    *(uint2*)((char*)Yt + off) = st;
  }
}

// ---------------- kernel 4: partial S = A_bin @ Z (bf16 MFMA) ----------------
// grid = B * 32 row-tiles * 4 k-splits = 512 blocks, 256 thr (4 waves x 2 strips)
__global__ __launch_bounds__(256) void k_spmm(const u64* __restrict__ bits,
                                              const unsigned short* __restrict__ Yt,
                                              float* __restrict__ Sp) {
  __shared__ __align__(16) unsigned short Zt[64 * 256]; // [d][256] raw-swizzled, 32KB
  __shared__ __align__(16) u64 Bl[128 * 4];             // [row][4 words], 4KB
  int bid = blockIdx.x;
  int split = bid & 3, tile = (bid >> 2) & 31, b = bid >> 7;
  int i0 = tile * 128;
  int tid = threadIdx.x, lane = tid & 63, wv = tid >> 6;
  int q = lane >> 4, ln = lane & 15;
  f32x4 acc[2][4];
#pragma unroll
  for (int s = 0; s < 2; ++s)
#pragma unroll
    for (int t = 0; t < 4; ++t) { acc[s][t][0]=0.f; acc[s][t][1]=0.f; acc[s][t][2]=0.f; acc[s][t][3]=0.f; }

  const char* ytp = (const char*)Yt + (size_t)b * 64 * (Nn * 2);
  const char* btp = (const char*)bits + ((size_t)b * Nn + i0) * 512;

  for (int it = 0; it < 4; ++it) {
    int kb = split * 1024 + it * 256;   // K-range start
    __syncthreads();                    // protect LDS from prev-iter readers
    int blk = kb >> 8;                  // 512B block index in Yt row
#pragma unroll
    for (int qq = 0; qq < 8; ++qq) {    // Zt: 32KB, wave-chunks of 1KB
      int c = wv * 8 + qq;
      int d = c * 2 + (lane >> 5);
      const char* g = ytp + (size_t)d * (Nn * 2) + ((size_t)blk << 9) + (size_t)(lane & 31) * 16;
      gll16(g, (char*)Zt + (size_t)c * 1024);
    }
    { // bits: 4KB
      int flat = wv * 64 + lane;
      const char* g = btp + (size_t)(flat >> 1) * 512 + (size_t)(kb >> 3) + (size_t)(flat & 1) * 16;
      gll16(g, (char*)Bl + (size_t)wv * 1024);
    }
    __builtin_amdgcn_s_waitcnt(0);
    __syncthreads();

    u64 wd[2];
#pragma unroll
    for (int kk = 0; kk < 8; ++kk) {
      short8 bf[4];
#pragma unroll
      for (int t = 0; t < 4; ++t) {
        int d = t * 16 + ln;
        int off = ((kk * 64 + q * 16) ^ ((d & 7) << 4)) + d * 512;
        bf[t] = *(short8*)((char*)Zt + off);
      }
      if ((kk & 1) == 0) {
#pragma unroll
        for (int s = 0; s < 2; ++s)
          wd[s] = Bl[(wv * 32 + s * 16 + ln) * 4 + (kk >> 1)];
      }
#pragma unroll
      for (int s = 0; s < 2; ++s) {
        u32 byte = (u32)(wd[s] >> (8 * (4 * (kk & 1) + q))) & 0xFFu;
        short8 af = expand_byte(byte);
#pragma unroll
        for (int t = 0; t < 4; ++t)
          acc[s][t] = __builtin_amdgcn_mfma_f32_16x16x32_bf16(af, bf[t], acc[s][t], 0, 0, 0);
      }
    }
  }
  float* outp = Sp + (size_t)split * TOT + ((size_t)b * Nn + i0) * Dd;
#pragma unroll
  for (int s = 0; s < 2; ++s)
#pragma unroll
    for (int t = 0; t < 4; ++t) {
      int rbase = wv * 32 + s * 16 + q * 4;
      int d = t * 16 + ln;
#pragma unroll
      for (int r = 0; r < 4; ++r)
        outp[(size_t)(rbase + r) * Dd + d] = acc[s][t][r];
    }
}

// ---------------- kernel 5: reduce partials + dinv*S + bias (+ELU+dropout) ----
__global__ __launch_bounds__(256) void k_epi(const float* __restrict__ Sp,
                                             const float* __restrict__ dinv,
                                             const float* __restrict__ bias,
                                             const unsigned char* __restrict__ mask,
                                             float* __restrict__ Hout, int mode) {
  int f = blockIdx.x * 256 + threadIdx.x;
  float s = Sp[f] + Sp[f + TOT] + Sp[f + 2 * TOT] + Sp[f + 3 * TOT];
  s = s * dinv[f >> 6] + bias[f & 63];
  if (mode) {
    float e = s > 0.f ? s : expm1f(s);
    s = mask[f] ? e * 1.25f : 0.f;      // /0.8 == *1.25 (exact)
  }
  Hout[f] = s;
}

// ---------------- launch ----------------
extern "C" void kernel_launch(void* const* d_in, const int* in_sizes, int n_in,
                              void* d_out, int out_size, void* d_ws, size_t ws_size,
                              hipStream_t stream) {
  const float* x  = (const float*)d_in[0];
  const int*   adj= (const int*)d_in[1];
  const float* W1 = (const float*)d_in[2];
  const float* b1 = (const float*)d_in[3];
  const float* W2 = (const float*)d_in[4];
  const float* b2 = (const float*)d_in[5];
  const float* W3 = (const float*)d_in[6];
  const float* b3 = (const float*)d_in[7];
  float* out = (float*)d_out;
  char* ws = (char*)d_ws;

  u64*            bits  = (u64*)(ws);                         // 8,388,608 B
  float*          dinv  = (float*)(ws + 8388608);             //    65,536 B
  unsigned char*  masks = (unsigned char*)(ws + 8454144);     // 2,097,152 B
  unsigned short* Yt    = (unsigned short*)(ws + 10551296);   // 2,097,152 B
  float*          H     = (float*)(ws + 12648448);            // 4,194,304 B
  float*          Sp    = (float*)(ws + 16842752);            //16,777,216 B

  k_bits<<<Bsz * Nn, 256, 0, stream>>>(adj, bits, dinv);
#if JAX_PARTITIONABLE
  k_masks<<<(2 * TOT) / 256, 256, 0, stream>>>(masks);
#else
  k_masks<<<(2 * HALF) / 256, 256, 0, stream>>>(masks);
#endif

  k_xw<<<(Bsz * Nn) / 64, 256, 0, stream>>>(x, W1, dinv, Yt);
  k_spmm<<<512, 256, 0, stream>>>(bits, Yt, Sp);
  k_epi<<<TOT / 256, 256, 0, stream>>>(Sp, dinv, b1, masks, H, 1);

  k_xw<<<(Bsz * Nn) / 64, 256, 0, stream>>>(H, W2, dinv, Yt);
  k_spmm<<<512, 256, 0, stream>>>(bits, Yt, Sp);
  k_epi<<<TOT / 256, 256, 0, stream>>>(Sp, dinv, b2, masks + TOT, H, 1);

  k_xw<<<(Bsz * Nn) / 64, 256, 0, stream>>>(H, W3, dinv, Yt);
  k_spmm<<<512, 256, 0, stream>>>(bits, Yt, Sp);
  k_epi<<<TOT / 256, 256, 0, stream>>>(Sp, dinv, b3, masks, out, 0);
}

// Round 2
// 457.840 us; speedup vs baseline: 1.0439x; 1.0439x over previous
//
#include <hip/hip_runtime.h>
#include <math.h>

// ---------------- config ----------------
// JAX dropout RNG scheme: 1 = jax_threefry_partitionable (modern default),
// 0 = original/legacy threefry counter layout. (1 verified correct R1.)
#define JAX_PARTITIONABLE 1

#define Bsz 4
#define Nn  4096
#define Dd  64
#define TOT (Bsz*Nn*Dd)          // 1048576
#define HALF (TOT/2)             // 524288

typedef unsigned int u32;
typedef unsigned long long u64;
typedef short short8 __attribute__((ext_vector_type(8)));
typedef float f32x4 __attribute__((ext_vector_type(4)));

// ---------------- helpers ----------------
__device__ __forceinline__ unsigned short bf16_of(float x) {
  u32 u = __float_as_uint(x);
  u32 r = (u + 0x7FFFu + ((u >> 16) & 1u)) >> 16;   // RNE
  return (unsigned short)r;
}
__device__ __forceinline__ u32 pack2(float a, float b) {
  return (u32)bf16_of(a) | ((u32)bf16_of(b) << 16);
}
__device__ __forceinline__ void gll16(const void* g, void* l) {
  // async global->LDS, 16B/lane, dest = wave-uniform base + lane*16
  __builtin_amdgcn_global_load_lds((const __attribute__((address_space(1))) void*)g,
                                   (__attribute__((address_space(3))) void*)l, 16, 0, 0);
}

// Threefry-2x32 (exact JAX rotation/key schedule)
__device__ __forceinline__ void tf(u32 k0, u32 k1, u32 x0, u32 x1, u32& y0, u32& y1) {
  u32 ks2 = k0 ^ k1 ^ 0x1BD11BDAu;
  x0 += k0; x1 += k1;
#define TFR(r) { x0 += x1; x1 = (x1 << (r)) | (x1 >> (32 - (r))); x1 ^= x0; }
  TFR(13) TFR(15) TFR(26) TFR(6)
  x0 += k1; x1 += ks2 + 1u;
  TFR(17) TFR(29) TFR(16) TFR(24)
  x0 += ks2; x1 += k0 + 2u;
  TFR(13) TFR(15) TFR(26) TFR(6)
  x0 += k0; x1 += k1 + 3u;
  TFR(17) TFR(29) TFR(16) TFR(24)
  x0 += k1; x1 += ks2 + 4u;
  TFR(13) TFR(15) TFR(26) TFR(6)
  x0 += ks2; x1 += k0 + 5u;
#undef TFR
  y0 = x0; y1 = x1;
}

// bit->bf16 expansion: byte (8 bits, tau-permuted at build time) -> 8 bf16 {0,1}
// element e <- byte bit tau(e), tau=(0,2,1,3,4,6,5,7) self-inverse.
__device__ __forceinline__ short8 expand_byte(u32 byte) {
  u32 lo = byte & 15u, hi = (byte >> 4) & 15u;
  u32 s0 = (lo * 0x00204081u) & 0x01010101u;
  u32 s1 = (hi * 0x00204081u) & 0x01010101u;
  union { u32 u[4]; short8 v; } r;
  r.u[0] = (s0 & 0x00010001u) * 0x3F80u;
  r.u[1] = ((s0 >> 8) & 0x00010001u) * 0x3F80u;
  r.u[2] = (s1 & 0x00010001u) * 0x3F80u;
  r.u[3] = ((s1 >> 8) & 0x00010001u) * 0x3F80u;
  return r.v;
}

// ---------------- kernel 1: adj -> bitmask + dinv (v2: no ballot) ----------
// one block per (b,i) row. Lane owns 16 consecutive columns (64B contiguous
// per lane = full cache lines; 4x dwordx4). Builds 2 tau-permuted bytes in
// register, coalesced u16 store. Byte-major layout identical to R1's ballot
// layout by construction: stored bit b of byte j8 = column 8*j8 + tau(b).
__global__ __launch_bounds__(256) void k_bits(const int* __restrict__ adj,
                                              u64* __restrict__ bits,
                                              float* __restrict__ dinv) {
  int row = blockIdx.x;              // b*N + i
  int i = row & (Nn - 1);
  int lane = threadIdx.x & 63;
  int wv = threadIdx.x >> 6;
  __shared__ int cnts[4];
  int col0 = wv * 1024 + lane * 16;  // first of 16 columns this thread owns
  const int4* rp = (const int4*)(adj + (size_t)row * Nn + col0);
  int4 a0 = rp[0];
  int4 a1 = rp[1];
  int4 a2 = rp[2];
  int4 a3 = rp[3];
  // tau bit positions for e=0..7: 0,2,1,3,4,6,5,7
  u32 v = 0;
  v |= (a0.x != 0) ? (1u << 0) : 0u;
  v |= (a0.y != 0) ? (1u << 2) : 0u;
  v |= (a0.z != 0) ? (1u << 1) : 0u;
  v |= (a0.w != 0) ? (1u << 3) : 0u;
  v |= (a1.x != 0) ? (1u << 4) : 0u;
  v |= (a1.y != 0) ? (1u << 6) : 0u;
  v |= (a1.z != 0) ? (1u << 5) : 0u;
  v |= (a1.w != 0) ? (1u << 7) : 0u;
  v |= (a2.x != 0) ? (1u << 8) : 0u;
  v |= (a2.y != 0) ? (1u << 10) : 0u;
  v |= (a2.z != 0) ? (1u << 9) : 0u;
  v |= (a2.w != 0) ? (1u << 11) : 0u;
  v |= (a3.x != 0) ? (1u << 12) : 0u;
  v |= (a3.y != 0) ? (1u << 14) : 0u;
  v |= (a3.z != 0) ? (1u << 13) : 0u;
  v |= (a3.w != 0) ? (1u << 15) : 0u;
  if ((i >> 4) == (col0 >> 4)) {     // self-loop column lands in my 16
    int e = i & 15;
    int e7 = e & 7;
    int m = ((e7 ^ (e7 >> 1)) & 1);
    int bit = (e & 8) + (e7 ^ (m * 3));   // (e&8) + tau(e&7)
    v |= 1u << bit;
  }
  ((unsigned short*)bits)[(size_t)row * 256 + (size_t)(wv * 64 + lane)] =
      (unsigned short)v;
  int c = __popc(v);
  c += __shfl_down(c, 32, 64);
  c += __shfl_down(c, 16, 64);
  c += __shfl_down(c, 8, 64);
  c += __shfl_down(c, 4, 64);
  c += __shfl_down(c, 2, 64);
  c += __shfl_down(c, 1, 64);
  if (lane == 0) cnts[wv] = c;
  __syncthreads();
  if (threadIdx.x == 0) {
    int deg = cnts[0] + cnts[1] + cnts[2] + cnts[3];
    dinv[row] = (float)(1.0 / sqrt((double)deg));
  }
}

// ---------------- kernel 2: dropout masks (exact JAX threefry) ----------------
__global__ __launch_bounds__(256) void k_masks(unsigned char* __restrict__ masks) {
#if JAX_PARTITIONABLE
  // split(key(42)) fold-like: key_i = threefry((0,42), (0, i)) full pair
  u32 k1a, k1b, k2a, k2b;
  tf(0u, 42u, 0u, 0u, k1a, k1b);
  tf(0u, 42u, 0u, 1u, k2a, k2b);
  int tid = blockIdx.x * 256 + threadIdx.x;     // [0, 2*TOT)
  int layer = tid >> 20;
  u32 f = (u32)(tid & (TOT - 1));
  u32 ka = layer ? k2a : k1a, kb = layer ? k2b : k1b;
  u32 h0, h1; tf(ka, kb, 0u, f, h0, h1);
  u32 bitsv = h0 ^ h1;                          // 32-bit fold
  float u = __uint_as_float((bitsv >> 9) | 0x3F800000u) - 1.0f;
  masks[tid] = (u < 0.8f) ? 1 : 0;
#else
  // legacy: split via iota(4) halves; bits via iota(TOT) halves
  u32 a0, b0, a1, b1;
  tf(0u, 42u, 0u, 2u, a0, b0);
  tf(0u, 42u, 1u, 3u, a1, b1);
  u32 k1a = a0, k1b = a1, k2a = b0, k2b = b1;
  int tid = blockIdx.x * 256 + threadIdx.x;     // [0, 2*HALF)
  int layer = tid >> 19;
  u32 p = (u32)(tid & (HALF - 1));
  u32 ka = layer ? k2a : k1a, kb = layer ? k2b : k1b;
  u32 y0, y1; tf(ka, kb, p, (u32)HALF + p, y0, y1);
  unsigned char* mb = masks + (size_t)layer * TOT;
  float u0 = __uint_as_float((y0 >> 9) | 0x3F800000u) - 1.0f;
  float u1 = __uint_as_float((y1 >> 9) | 0x3F800000u) - 1.0f;
  mb[p] = (u0 < 0.8f) ? 1 : 0;
  mb[p + HALF] = (u1 < 0.8f) ? 1 : 0;
#endif
}

// ---------------- kernel 3: Yt = swizzled-transpose( dinv .* (X @ W) ) bf16 ----
// 64-row tile per block; MFMA 16x16x32 bf16.
__global__ __launch_bounds__(256) void k_xw(const float* __restrict__ X,
                                            const float* __restrict__ W,
                                            const float* __restrict__ dinv,
                                            unsigned short* __restrict__ Yt) {
  __shared__ __align__(16) unsigned short Xl[64][72];  // +8 pad: stride 144B (=16 mod 128)
  __shared__ __align__(16) unsigned short Wt[64][72];  // W transposed [d][k]
  __shared__ float dl[64];
  int tid = threadIdx.x;
  int gi0 = blockIdx.x * 64;            // global row b*N + i
#pragma unroll
  for (int it = 0; it < 8; ++it) {      // X tile: 2048 bf16-pairs
    int p = it * 256 + tid;
    int r = p >> 5, c2 = (p & 31) * 2;
    const float* src = X + (size_t)(gi0 + r) * Dd + c2;
    *(u32*)&Xl[r][c2] = pack2(src[0], src[1]);
  }
#pragma unroll
  for (int it = 0; it < 16; ++it) {     // W: 4096 elems, transposed into Wt[d][k]
    int e = it * 256 + tid;
    int k = e >> 6, d = e & 63;
    Wt[d][k] = bf16_of(W[e]);
  }
  if (tid < 64) dl[tid] = dinv[gi0 + tid];
  __syncthreads();

  int lane = tid & 63, wv = tid >> 6;
  int q = lane >> 4, ln = lane & 15;
  f32x4 acc[4];
#pragma unroll
  for (int t = 0; t < 4; ++t) { acc[t][0]=0.f; acc[t][1]=0.f; acc[t][2]=0.f; acc[t][3]=0.f; }
#pragma unroll
  for (int ks = 0; ks < 2; ++ks) {
    short8 a = *(short8*)&Xl[wv * 16 + ln][ks * 32 + q * 8];
#pragma unroll
    for (int t = 0; t < 4; ++t) {
      short8 bfr = *(short8*)&Wt[t * 16 + ln][ks * 32 + q * 8];
      acc[t] = __builtin_amdgcn_mfma_f32_16x16x32_bf16(a, bfr, acc[t], 0, 0, 0);
    }
  }
  int b = gi0 >> 12;
  int i_in_b = gi0 & (Nn - 1);
#pragma unroll
  for (int t = 0; t < 4; ++t) {
    int d = t * 16 + ln;
    int j0 = i_in_b + wv * 16 + q * 4;  // node index of first of 4 rows
    unsigned short h[4];
#pragma unroll
    for (int r = 0; r < 4; ++r) h[r] = bf16_of(acc[t][r] * dl[wv * 16 + q * 4 + r]);
    int byte0 = (2 * j0) & 511;
    int blk = (2 * j0) >> 9;
    size_t off = ((size_t)b * 64 + d) * (Nn * 2) + ((size_t)blk << 9)
               + (size_t)(byte0 ^ ((d & 7) << 4));     // XOR swizzle per d
    uint2 st; st.x = (u32)h[0] | ((u32)h[1] << 16); st.y = (u32)h[2] | ((u32)h[3] << 16);
    *(uint2*)((char*)Yt + off) = st;
  }
}

// ---------------- kernel 4: partial S = A_bin @ Z (bf16 MFMA) ----------------
// grid = B * 32 row-tiles * 4 k-splits = 512 blocks, 256 thr (4 waves x 2 strips)
__global__ __launch_bounds__(256) void k_spmm(const u64* __restrict__ bits,
                                              const unsigned short* __restrict__ Yt,
                                              float* __restrict__ Sp) {
  __shared__ __align__(16) unsigned short Zt[64 * 256]; // [d][256] raw-swizzled, 32KB
  __shared__ __align__(16) u64 Bl[128 * 4];             // [row][4 words], 4KB
  int bid = blockIdx.x;
  int split = bid & 3, tile = (bid >> 2) & 31, b = bid >> 7;
  int i0 = tile * 128;
  int tid = threadIdx.x, lane = tid & 63, wv = tid >> 6;
  int q = lane >> 4, ln = lane & 15;
  f32x4 acc[2][4];
#pragma unroll
  for (int s = 0; s < 2; ++s)
#pragma unroll
    for (int t = 0; t < 4; ++t) { acc[s][t][0]=0.f; acc[s][t][1]=0.f; acc[s][t][2]=0.f; acc[s][t][3]=0.f; }

  const char* ytp = (const char*)Yt + (size_t)b * 64 * (Nn * 2);
  const char* btp = (const char*)bits + ((size_t)b * Nn + i0) * 512;

  for (int it = 0; it < 4; ++it) {
    int kb = split * 1024 + it * 256;   // K-range start
    __syncthreads();                    // protect LDS from prev-iter readers
    int blk = kb >> 8;                  // 512B block index in Yt row
#pragma unroll
    for (int qq = 0; qq < 8; ++qq) {    // Zt: 32KB, wave-chunks of 1KB
      int c = wv * 8 + qq;
      int d = c * 2 + (lane >> 5);
      const char* g = ytp + (size_t)d * (Nn * 2) + ((size_t)blk << 9) + (size_t)(lane & 31) * 16;
      gll16(g, (char*)Zt + (size_t)c * 1024);
    }
    { // bits: 4KB
      int flat = wv * 64 + lane;
      const char* g = btp + (size_t)(flat >> 1) * 512 + (size_t)(kb >> 3) + (size_t)(flat & 1) * 16;
      gll16(g, (char*)Bl + (size_t)wv * 1024);
    }
    __builtin_amdgcn_s_waitcnt(0);
    __syncthreads();

    u64 wd[2];
#pragma unroll
    for (int kk = 0; kk < 8; ++kk) {
      short8 bf[4];
#pragma unroll
      for (int t = 0; t < 4; ++t) {
        int d = t * 16 + ln;
        int off = ((kk * 64 + q * 16) ^ ((d & 7) << 4)) + d * 512;
        bf[t] = *(short8*)((char*)Zt + off);
      }
      if ((kk & 1) == 0) {
#pragma unroll
        for (int s = 0; s < 2; ++s)
          wd[s] = Bl[(wv * 32 + s * 16 + ln) * 4 + (kk >> 1)];
      }
#pragma unroll
      for (int s = 0; s < 2; ++s) {
        u32 byte = (u32)(wd[s] >> (8 * (4 * (kk & 1) + q))) & 0xFFu;
        short8 af = expand_byte(byte);
#pragma unroll
        for (int t = 0; t < 4; ++t)
          acc[s][t] = __builtin_amdgcn_mfma_f32_16x16x32_bf16(af, bf[t], acc[s][t], 0, 0, 0);
      }
    }
  }
  float* outp = Sp + (size_t)split * TOT + ((size_t)b * Nn + i0) * Dd;
#pragma unroll
  for (int s = 0; s < 2; ++s)
#pragma unroll
    for (int t = 0; t < 4; ++t) {
      int rbase = wv * 32 + s * 16 + q * 4;
      int d = t * 16 + ln;
#pragma unroll
      for (int r = 0; r < 4; ++r)
        outp[(size_t)(rbase + r) * Dd + d] = acc[s][t][r];
    }
}

// ---------------- kernel 5: reduce partials + dinv*S + bias (+ELU+dropout) ----
__global__ __launch_bounds__(256) void k_epi(const float* __restrict__ Sp,
                                             const float* __restrict__ dinv,
                                             const float* __restrict__ bias,
                                             const unsigned char* __restrict__ mask,
                                             float* __restrict__ Hout, int mode) {
  int f = blockIdx.x * 256 + threadIdx.x;
  float s = Sp[f] + Sp[f + TOT] + Sp[f + 2 * TOT] + Sp[f + 3 * TOT];
  s = s * dinv[f >> 6] + bias[f & 63];
  if (mode) {
    float e = s > 0.f ? s : expm1f(s);
    s = mask[f] ? e * 1.25f : 0.f;      // /0.8 == *1.25 (exact)
  }
  Hout[f] = s;
}

// ---------------- launch ----------------
extern "C" void kernel_launch(void* const* d_in, const int* in_sizes, int n_in,
                              void* d_out, int out_size, void* d_ws, size_t ws_size,
                              hipStream_t stream) {
  const float* x  = (const float*)d_in[0];
  const int*   adj= (const int*)d_in[1];
  const float* W1 = (const float*)d_in[2];
  const float* b1 = (const float*)d_in[3];
  const float* W2 = (const float*)d_in[4];
  const float* b2 = (const float*)d_in[5];
  const float* W3 = (const float*)d_in[6];
  const float* b3 = (const float*)d_in[7];
  float* out = (float*)d_out;
  char* ws = (char*)d_ws;

  u64*            bits  = (u64*)(ws);                         // 8,388,608 B
  float*          dinv  = (float*)(ws + 8388608);             //    65,536 B
  unsigned char*  masks = (unsigned char*)(ws + 8454144);     // 2,097,152 B
  unsigned short* Yt    = (unsigned short*)(ws + 10551296);   // 2,097,152 B
  float*          H     = (float*)(ws + 12648448);            // 4,194,304 B
  float*          Sp    = (float*)(ws + 16842752);            //16,777,216 B

  k_bits<<<Bsz * Nn, 256, 0, stream>>>(adj, bits, dinv);
#if JAX_PARTITIONABLE
  k_masks<<<(2 * TOT) / 256, 256, 0, stream>>>(masks);
#else
  k_masks<<<(2 * HALF) / 256, 256, 0, stream>>>(masks);
#endif

  k_xw<<<(Bsz * Nn) / 64, 256, 0, stream>>>(x, W1, dinv, Yt);
  k_spmm<<<512, 256, 0, stream>>>(bits, Yt, Sp);
  k_epi<<<TOT / 256, 256, 0, stream>>>(Sp, dinv, b1, masks, H, 1);

  k_xw<<<(Bsz * Nn) / 64, 256, 0, stream>>>(H, W2, dinv, Yt);
  k_spmm<<<512, 256, 0, stream>>>(bits, Yt, Sp);
  k_epi<<<TOT / 256, 256, 0, stream>>>(Sp, dinv, b2, masks + TOT, H, 1);

  k_xw<<<(Bsz * Nn) / 64, 256, 0, stream>>>(H, W3, dinv, Yt);
  k_spmm<<<512, 256, 0, stream>>>(bits, Yt, Sp);
  k_epi<<<TOT / 256, 256, 0, stream>>>(Sp, dinv, b3, masks, out, 0);
}